// Round 15
// baseline (226.348 us; speedup 1.0000x reference)
//
#include <hip/hip_runtime.h>
#include <float.h>
#include <math.h>

#define NPTS 4096
#define NBATCH 4
#define BN (NBATCH * NPTS)   // 16384
#define EPSC 1e-12f
#define CSTRIDE 204          // ushort row stride of the bf16x3 image

typedef __attribute__((ext_vector_type(8))) short bfrag;   // 8 bf16 (4 VGPR) MFMA operand
typedef __attribute__((ext_vector_type(4))) short bhalf;   // 8B half-fragment
typedef __attribute__((ext_vector_type(4))) float f32x4;   // MFMA accumulator

#define MFMA(A, B, C) __builtin_amdgcn_mfma_f32_16x16x32_bf16((A), (B), (C), 0, 0, 0)

__device__ __forceinline__ bool dless(float d1, int i1, float d2, int i2) {
  return (d1 < d2) || ((d1 == d2) && (i1 < i2));
}

// RN-even fp32->bf16 (branch-free), and back
__device__ __forceinline__ unsigned short f2bf(float x) {
  unsigned b = __float_as_uint(x);
  return (unsigned short)((b + 0x7FFFu + ((b >> 16) & 1u)) >> 16);
}
__device__ __forceinline__ float bf2f(unsigned short u) {
  return __uint_as_float(((unsigned)u) << 16);
}
__device__ __forceinline__ void bf3(float x, unsigned short& u0, unsigned short& u1,
                                    unsigned short& u2) {
  u0 = f2bf(x);
  float r = x - bf2f(u0);
  u1 = f2bf(r);
  r = r - bf2f(u1);
  u2 = f2bf(r);
}

// async global->LDS copies (no VGPR round-trip; wave-uniform base + lane*size)
__device__ __forceinline__ void cp16(const void* g, void* l) {
  __builtin_amdgcn_global_load_lds(
      (const __attribute__((address_space(1))) unsigned int*)g,
      (__attribute__((address_space(3))) unsigned int*)l, 16, 0, 0);
}
__device__ __forceinline__ void cp4(const void* g, void* l) {
  __builtin_amdgcn_global_load_lds(
      (const __attribute__((address_space(1))) unsigned int*)g,
      (__attribute__((address_space(3))) unsigned int*)l, 4, 0, 0);
}

// generic WAYS-way lex-merge of sorted 10-lists (constant-index heads, no scratch)
template <int WAYS, typename TD, typename TI>
__device__ __forceinline__ void merge_ways(const TD* td, const TI* ti,
                                           float* dk, int* ik) {
  int hh[WAYS];
#pragma unroll
  for (int i = 0; i < WAYS; ++i) hh[i] = 0;
#pragma unroll
  for (int k = 0; k < 10; ++k) {
    float bd = FLT_MAX;
    int bi = 0x7fffffff, bl = -1;
#pragma unroll
    for (int m = 0; m < WAYS; ++m) {
      float d = (float)td[10 * m + hh[m]];
      int ii = (int)ti[10 * m + hh[m]];
      if (dless(d, ii, bd, bi)) { bd = d; bi = ii; bl = m; }
    }
#pragma unroll
    for (int m = 0; m < WAYS; ++m) hh[m] += (bl == m);
    dk[k] = bd;
    ik[k] = bi;
  }
}

// ---------------------------------------------------------------------------
// Kernel 1: fused MLP + bf16x3 row-layout image — e, logits, sq, nd, cbf.
// ---------------------------------------------------------------------------
__device__ __forceinline__ void gemm32x128(const float (*A)[64], const float* W,
                                           const float* bias, float (*O)[128], int tid) {
  const int pi = (tid >> 5) << 2;
  const int ci = (tid & 31) << 2;
  float acc[4][4] = {};
  for (int k0 = 0; k0 < 64; k0 += 4) {
    alignas(16) float av[4][4], wv[4][4];
#pragma unroll
    for (int r = 0; r < 4; ++r) *(float4*)av[r] = *(const float4*)&A[pi + r][k0];
#pragma unroll
    for (int kk = 0; kk < 4; ++kk) *(float4*)wv[kk] = *(const float4*)&W[(k0 + kk) * 128 + ci];
#pragma unroll
    for (int kk = 0; kk < 4; ++kk)
#pragma unroll
      for (int r = 0; r < 4; ++r)
#pragma unroll
        for (int c = 0; c < 4; ++c)
          acc[r][c] = fmaf(av[r][kk], wv[kk][c], acc[r][c]);
  }
#pragma unroll
  for (int r = 0; r < 4; ++r)
#pragma unroll
    for (int c = 0; c < 4; ++c)
      O[pi + r][ci + c] = fmaxf(acc[r][c] + bias[ci + c], 0.f);
}

__global__ __launch_bounds__(256) void mlp_kernel(
    const float* __restrict__ conf, const float* __restrict__ native,
    const float* __restrict__ We1, const float* __restrict__ be1,
    const float* __restrict__ We2, const float* __restrict__ be2,
    const float* __restrict__ We3, const float* __restrict__ be3,
    const float* __restrict__ Ws1, const float* __restrict__ bs1,
    const float* __restrict__ Ws2, const float* __restrict__ bs2,
    float* __restrict__ e_out, float* __restrict__ logits_out,
    float* __restrict__ sq_ws, float* __restrict__ nd_ws,
    unsigned short* __restrict__ cbf) {
  __shared__ __align__(16) float Wbuf[8192];
  __shared__ __align__(16) float confs[32][64];
  __shared__ __align__(16) float hbuf[32][128];
  __shared__ float nat[64];
  __shared__ float b1s[128], b2s[64], w3s[64], bs1s[128], ws2s[768], bs2s[6];
  __shared__ float be3s;

  const int tid = threadIdx.x;
  const int blk = blockIdx.x;
  const int b = blk >> 7;
  const int pbase = (blk & 127) * 32;
  const float* confb = conf + ((size_t)b * NPTS + pbase) * 64;

  for (int q = tid; q < 512; q += 256) {
    float4 v = *(const float4*)(confb + q * 4);
    *(float4*)&confs[q >> 4][(q & 15) << 2] = v;
  }
  if (tid < 64) nat[tid] = native[b * 64 + tid];
  if (tid < 128) b1s[tid] = be1[tid];
  if (tid < 64) b2s[tid] = be2[tid];
  if (tid < 64) w3s[tid] = We3[tid];
  if (tid < 128) bs1s[tid] = bs1[tid];
  for (int q = tid; q < 768; q += 256) ws2s[q] = Ws2[q];
  if (tid < 6) bs2s[tid] = bs2[tid];
  if (tid == 0) be3s = be3[0];
  for (int q = tid; q < 2048; q += 256)
    *(float4*)&Wbuf[q * 4] = *(const float4*)(Ws1 + q * 4);
  __syncthreads();

  // bf16x3 image of this 32-point tile (row layout, same bits as prior rounds)
  for (int q = tid; q < 512; q += 256) {
    const int pl = q >> 4, k4 = (q & 15) << 2;
    float4 v = *(const float4*)&confs[pl][k4];
    unsigned short x0, x1, x2, y0, y1, y2, z0, z1, z2, w0, w1, w2;
    bf3(v.x, x0, x1, x2);
    bf3(v.y, y0, y1, y2);
    bf3(v.z, z0, z1, z2);
    bf3(v.w, w0, w1, w2);
    unsigned short* dst = cbf + (size_t)(b * NPTS + pbase + pl) * CSTRIDE + k4;
    *(bhalf*)&dst[0] = (bhalf){(short)x0, (short)y0, (short)z0, (short)w0};
    *(bhalf*)&dst[64] = (bhalf){(short)x1, (short)y1, (short)z1, (short)w1};
    *(bhalf*)&dst[128] = (bhalf){(short)x2, (short)y2, (short)z2, (short)w2};
  }

  // sq & nd — numpy-pairwise style: rounded products, 8 accumulators
  if (tid < 32) {
    float rs_[8], rn_[8];
#pragma unroll
    for (int u = 0; u < 8; ++u) {
      float c = confs[tid][u];
      rs_[u] = c * c;
      float d = c - nat[u];
      rn_[u] = d * d;
    }
    for (int d0 = 8; d0 < 64; d0 += 8) {
#pragma unroll
      for (int u = 0; u < 8; ++u) {
        float c = confs[tid][d0 + u];
        rs_[u] += c * c;
        float d = c - nat[d0 + u];
        rn_[u] += d * d;
      }
    }
    float s = ((rs_[0] + rs_[1]) + (rs_[2] + rs_[3])) + ((rs_[4] + rs_[5]) + (rs_[6] + rs_[7]));
    float n = ((rn_[0] + rn_[1]) + (rn_[2] + rn_[3])) + ((rn_[4] + rn_[5]) + (rn_[6] + rn_[7]));
    sq_ws[(size_t)b * NPTS + pbase + tid] = s;
    nd_ws[(size_t)b * NPTS + pbase + tid] = sqrtf(n);
  }

  gemm32x128(confs, Wbuf, bs1s, hbuf, tid);     // g = relu(conf @ Ws1 + bs1)
  __syncthreads();

  for (int q = tid; q < 2048; q += 256)         // reload Wbuf <- We1
    *(float4*)&Wbuf[q * 4] = *(const float4*)(We1 + q * 4);
  if (tid < 192) {
    int p = tid / 6, s = tid % 6;
    float acc = 0.f;
#pragma unroll 8
    for (int h = 0; h < 128; ++h)
      acc = fmaf(hbuf[p][h], ws2s[h * 6 + s], acc);
    logits_out[((size_t)b * NPTS + pbase + p) * 6 + s] = acc + bs2s[s];
  }
  __syncthreads();

  gemm32x128(confs, Wbuf, b1s, hbuf, tid);      // h1 = relu(conf @ We1 + be1)
  __syncthreads();

  for (int q = tid; q < 2048; q += 256)
    *(float4*)&Wbuf[q * 4] = *(const float4*)(We2 + q * 4);
  __syncthreads();

  // h2 = relu(h1 @ We2 + be2) -> confs
  if (tid < 128) {
    const int pi = (tid >> 4) << 2;
    const int ci = (tid & 15) << 2;
    float acc[4][4] = {};
    for (int k0 = 0; k0 < 128; k0 += 4) {
      alignas(16) float av[4][4], wv[4][4];
#pragma unroll
      for (int r = 0; r < 4; ++r) *(float4*)av[r] = *(const float4*)&hbuf[pi + r][k0];
#pragma unroll
      for (int kk = 0; kk < 4; ++kk) *(float4*)wv[kk] = *(const float4*)&Wbuf[(k0 + kk) * 64 + ci];
#pragma unroll
      for (int kk = 0; kk < 4; ++kk)
#pragma unroll
        for (int r = 0; r < 4; ++r)
#pragma unroll
          for (int c = 0; c < 4; ++c)
            acc[r][c] = fmaf(av[r][kk], wv[kk][c], acc[r][c]);
    }
#pragma unroll
    for (int r = 0; r < 4; ++r)
#pragma unroll
      for (int c = 0; c < 4; ++c)
        confs[pi + r][ci + c] = fmaxf(acc[r][c] + b2s[ci + c], 0.f);
  }
  __syncthreads();

  if (tid < 32) {                               // e = h2 @ We3 + be3
    float acc = 0.f;
#pragma unroll
    for (int k = 0; k < 64; ++k)
      acc = fmaf(confs[tid][k], w3s[k], acc);
    e_out[(size_t)b * NPTS + pbase + tid] = acc + be3s;
  }
}

// ---------------------------------------------------------------------------
// Distance pass (split-j, templated JS), bf16x3 MFMA, d2-keyed, mask-queued
// top-10. R12 structure: BU staged via global_load_lds, serialized 4-subtile
// MFMA, pipelined drain. JS=8 halves block duration (grid 2048) to smooth
// round quantization; JS=4 is the exact R12 kernel (ws fallback).
// ---------------------------------------------------------------------------
__device__ __forceinline__ bfrag ldfrag(const unsigned short* p) {
  bhalf lo = *(const bhalf*)p;
  bhalf hi = *(const bhalf*)(p + 4);
  return __builtin_shufflevector(lo, hi, 0, 1, 2, 3, 4, 5, 6, 7);
}

__device__ __forceinline__ void stage_async(const unsigned short* src,
                                            unsigned short* BU,
                                            const float* sqsrc, float* sqjs,
                                            int tid) {
  const char* s = (const char*)src;
  char* d = (char*)BU;
#pragma unroll
  for (int it = 0; it < 6; ++it) {
    const int q = it * 256 + tid;
    cp16(s + (size_t)q * 16, d + (size_t)q * 16);
  }
  if (tid < 96) {
    const int q = 1536 + tid;
    cp16(s + (size_t)q * 16, d + (size_t)q * 16);
  }
  if (tid < 64) cp4(sqsrc + tid, sqjs + tid);
}

template <int JSV>
__global__ __launch_bounds__(256, 1) void topk_part_kernel(
    const unsigned short* __restrict__ cbf, const float* __restrict__ sq_ws,
    float* __restrict__ topd, unsigned short* __restrict__ topi) {
  constexpr int NTT = NPTS / JSV / 64;
  __shared__ __align__(16) unsigned short BU[64 * CSTRIDE];  // 26112 B
  __shared__ __align__(16) float Dsf[64 * 68];               // 17408 B
  __shared__ float sqjs[64];

  const int tid = threadIdx.x;
  const int b = blockIdx.z;
  const int i0 = blockIdx.x * 64;
  const int jbase = blockIdx.y * (NPTS / JSV);
  const unsigned short* cbfb = cbf + (size_t)b * NPTS * CSTRIDE;
  const float* sqb = sq_ws + (size_t)b * NPTS;

  const int l = tid & 63, w = tid >> 6;
  const int cl = l & 15, g = l >> 4;

  // A-fragments straight from global (one-time)
  const unsigned short* arow = cbfb + (size_t)(i0 + 16 * w + cl) * CSTRIDE + g * 8;
  const bfrag a00 = ldfrag(arow + 0);
  const bfrag a01 = ldfrag(arow + 32);
  const bfrag a10 = ldfrag(arow + 64);
  const bfrag a11 = ldfrag(arow + 96);
  const bfrag a20 = ldfrag(arow + 128);
  const bfrag a21 = ldfrag(arow + 160);
  float sqar[4];
#pragma unroll
  for (int e = 0; e < 4; ++e) sqar[e] = sqb[i0 + 16 * w + 4 * g + e];

  const int irow = tid >> 2, q4 = tid & 3;

  unsigned long long lk[10];
#pragma unroll
  for (int k = 0; k < 10; ++k) lk[k] = 0x7F7FFFFF7FFFFFFFULL;
  float thrf = FLT_MAX;

  stage_async(cbfb + (size_t)jbase * CSTRIDE, BU, sqb + jbase, sqjs, tid);
  __syncthreads();

  for (int jt = 0; jt < NTT; ++jt) {
    const int j0 = jbase + jt * 64;

    // ---- MFMA: 4 col-subtiles of 16, 12 k-steps each
#pragma unroll
    for (int c = 0; c < 4; ++c) {
      const unsigned short* bp = &BU[(16 * c + cl) * CSTRIDE + g * 8];
      const bfrag b00 = ldfrag(bp + 0);
      const bfrag b01 = ldfrag(bp + 32);
      const bfrag b10 = ldfrag(bp + 64);
      const bfrag b11 = ldfrag(bp + 96);
      const bfrag b20 = ldfrag(bp + 128);
      const bfrag b21 = ldfrag(bp + 160);
      f32x4 acc = {0.f, 0.f, 0.f, 0.f};
      acc = MFMA(a00, b00, acc); acc = MFMA(a01, b01, acc);   // A0*B0
      acc = MFMA(a00, b10, acc); acc = MFMA(a01, b11, acc);   // A0*B1
      acc = MFMA(a10, b00, acc); acc = MFMA(a11, b01, acc);   // A1*B0
      acc = MFMA(a00, b20, acc); acc = MFMA(a01, b21, acc);   // A0*B2
      acc = MFMA(a10, b10, acc); acc = MFMA(a11, b11, acc);   // A1*B1
      acc = MFMA(a20, b00, acc); acc = MFMA(a21, b01, acc);   // A2*B0
      const int col = 16 * c + cl;
      const float sj = sqjs[col];
#pragma unroll
      for (int e = 0; e < 4; ++e) {
        const int rw = 16 * w + 4 * g + e;
        float d2 = fmaf(-2.f, acc[e], sqar[e] + sj);
        Dsf[rw * 68 + col] = fmaxf(d2, EPSC);
      }
    }
    __syncthreads();

    if (jt + 1 < NTT)
      stage_async(cbfb + (size_t)(j0 + 64) * CSTRIDE, BU, sqb + j0 + 64, sqjs, tid);

    // ---- queue phase: 16-bit pass mask (ascending bit = ascending j)
    const float* drow = &Dsf[irow * 68 + q4 * 16];
    unsigned mask = 0;
#pragma unroll
    for (int cc = 0; cc < 4; ++cc) {
      float4 v = *(const float4*)&drow[cc * 4];
      mask |= (v.x <= thrf) ? (1u << (cc * 4 + 0)) : 0u;
      mask |= (v.y <= thrf) ? (1u << (cc * 4 + 1)) : 0u;
      mask |= (v.z <= thrf) ? (1u << (cc * 4 + 2)) : 0u;
      mask |= (v.w <= thrf) ? (1u << (cc * 4 + 3)) : 0u;
    }
    const int cnt = __popc(mask);
    int K = cnt;
#pragma unroll
    for (int off = 32; off >= 1; off >>= 1) K = max(K, __shfl_xor(K, off, 64));

    // ---- pipelined drain
    int id = (__ffs(mask) - 1) & 15;
    mask &= mask - 1;
    float dcur = drow[id];
    int jcur = j0 + q4 * 16 + id;
    for (int k = 0; k < K; ++k) {
      const int idn = (__ffs(mask) - 1) & 15;
      mask &= mask - 1;
      const float dnx = drow[idn];
      const int jnx = j0 + q4 * 16 + idn;
      if (k < cnt) {
        unsigned long long cur =
            (((unsigned long long)__float_as_uint(dcur)) << 32) |
            (unsigned long long)(unsigned)jcur;
        if (cur < lk[9]) {
#pragma unroll
          for (int kk = 0; kk < 10; ++kk) {
            bool lt = cur < lk[kk];
            unsigned long long mn = lt ? cur : lk[kk];
            cur = lt ? lk[kk] : cur;
            lk[kk] = mn;
          }
        }
      }
      dcur = dnx;
      jcur = jnx;
    }

    float t = __uint_as_float((unsigned)(lk[9] >> 32));
    t = fminf(t, __shfl_xor(t, 1, 4));
    t = fminf(t, __shfl_xor(t, 2, 4));
    thrf = t;
    __syncthreads();
  }

  // merge 4 per-thread sorted lists per row -> chunk top-10 (cd2)
  float* mrgD = Dsf;
  int* mrgI = (int*)BU;
  {
#pragma unroll
    for (int k = 0; k < 10; ++k) {
      mrgD[irow * 40 + q4 * 10 + k] = __uint_as_float((unsigned)(lk[k] >> 32));
      mrgI[irow * 40 + q4 * 10 + k] = (int)(unsigned)(lk[k] & 0xFFFFFFFFu);
    }
  }
  __syncthreads();
  if (tid < 64) {
    float dk[10];
    int ik[10];
    merge_ways<4>(&mrgD[tid * 40], &mrgI[tid * 40], dk, ik);
    const size_t obase = (((size_t)b * NPTS + i0 + tid) * JSV + blockIdx.y) * 10;
#pragma unroll
    for (int k = 0; k < 10; ++k) {
      topd[obase + k] = dk[k];
      topi[obase + k] = (unsigned short)ik[k];
    }
  }
}

// ---------------------------------------------------------------------------
// Fused merge (blocks 0..63) + rank (blocks 64..319), templated JS.
// ---------------------------------------------------------------------------
template <int JSV>
__global__ __launch_bounds__(256) void merge_rank_kernel(
    const float* __restrict__ topd, const unsigned short* __restrict__ topi,
    const float* __restrict__ e_in, const float* __restrict__ nd_ws,
    float* __restrict__ basin_out, float* __restrict__ depth_out,
    float* __restrict__ width_out, float* __restrict__ se_ws) {
  __shared__ __align__(16) float ndl[4096];
  const int tid = threadIdx.x;
  if (blockIdx.x < 64) {
    const int g = blockIdx.x * 256 + tid;
    const int b = g >> 12;
    const float* eb = e_in + (size_t)b * NPTS;
    const float* td = topd + (size_t)g * (JSV * 10);
    const unsigned short* ti = topi + (size_t)g * (JSV * 10);
    const float e_i = eb[g & (NPTS - 1)];
    float dk[10];
    int ik[10];
    merge_ways<JSV>(td, ti, dk, ik);
    const float r2 = dk[9];
    bool basin = true;
    float mx = -FLT_MAX, sum = 0.f, cnt = 0.f;
#pragma unroll
    for (int k = 0; k < 10; ++k) {
      float ev = eb[ik[k]];
      if (dk[k] < r2) { mx = fmaxf(mx, ev); sum += sqrtf(dk[k]); cnt += 1.f; }
      if (k >= 1) basin = basin && (e_i <= ev);
    }
    basin_out[g] = basin ? 1.f : 0.f;
    depth_out[g] = mx - e_i;
    width_out[g] = sum / cnt;
  } else {
    const int rb = blockIdx.x - 64;
    const int b = rb >> 6;
    const int i0 = (rb & 63) * 64;
    const float* ndb = nd_ws + (size_t)b * NPTS;
    for (int q = tid; q < 1024; q += 256)
      *(float4*)&ndl[q * 4] = *(const float4*)(ndb + q * 4);
    __syncthreads();
    const int i = i0 + (tid >> 2);
    const int qp = tid & 3;
    const float ndi = ndl[i];
    int rank = 0;
    for (int j = qp * 1024; j < qp * 1024 + 1024; j += 4) {
      float4 v = *(const float4*)&ndl[j];
      rank += (v.x < ndi) || (v.x == ndi && (j + 0) < i);
      rank += (v.y < ndi) || (v.y == ndi && (j + 1) < i);
      rank += (v.z < ndi) || (v.z == ndi && (j + 2) < i);
      rank += (v.w < ndi) || (v.w == ndi && (j + 3) < i);
    }
    rank += __shfl_xor(rank, 1, 4);
    rank += __shfl_xor(rank, 2, 4);
    if (qp == 0) se_ws[(size_t)b * NPTS + rank] = e_in[(size_t)b * NPTS + i];
  }
}

// ---------------------------------------------------------------------------
// Kernel 4: per-batch scalar metrics — wave-level reductions
// ---------------------------------------------------------------------------
__device__ __forceinline__ float wave_sum(float v) {
#pragma unroll
  for (int off = 32; off >= 1; off >>= 1) v += __shfl_xor(v, off, 64);
  return v;
}
__device__ __forceinline__ float wave_max(float v) {
#pragma unroll
  for (int off = 32; off >= 1; off >>= 1) v = fmaxf(v, __shfl_xor(v, off, 64));
  return v;
}

__global__ __launch_bounds__(1024) void metrics_kernel(
    const float* __restrict__ e_in, const float* __restrict__ nd_ws,
    const float* __restrict__ se_ws, float* __restrict__ metrics_out) {
  __shared__ __align__(16) float el[4096], ndl[4096], sel[4096];
  __shared__ float rA[16], rB[16], rC[16], rD[16], rE[16], rV[16];
  __shared__ int rI[16];
  const int tid = threadIdx.x;
  const int b = blockIdx.x;
  const int wid = tid >> 6, ln = tid & 63;
  const float* eb = e_in + (size_t)b * NPTS;
  const float* ndb = nd_ws + (size_t)b * NPTS;
  const float* seb = se_ws + (size_t)b * NPTS;
  *(float4*)&el[tid * 4] = *(const float4*)(eb + tid * 4);
  *(float4*)&ndl[tid * 4] = *(const float4*)(ndb + tid * 4);
  *(float4*)&sel[tid * 4] = *(const float4*)(seb + tid * 4);
  __syncthreads();

  float pe = 0.f, pnd = 0.f;
  for (int p = tid; p < 4096; p += 1024) { pe += el[p]; pnd += ndl[p]; }
  pe = wave_sum(pe);
  pnd = wave_sum(pnd);
  if (ln == 0) { rA[wid] = pe; rB[wid] = pnd; }
  __syncthreads();
  float me = 0.f, mnd = 0.f;
  for (int i = 0; i < 16; ++i) { me += rA[i]; mnd += rB[i]; }
  me /= 4096.f;
  mnd /= 4096.f;
  __syncthreads();

  float sxx = 0.f, syy = 0.f, sxy = 0.f, mx = -FLT_MAX;
  float bestv = FLT_MAX;
  int besti = 0x7fffffff;
  for (int p = tid; p < 4096; p += 1024) {
    float de = el[p] - me, dn = ndl[p] - mnd;
    syy += de * de;
    sxx += dn * dn;
    sxy += de * dn;
    mx = fmaxf(mx, el[p]);
    if (ndl[p] < bestv || (ndl[p] == bestv && p < besti)) { bestv = ndl[p]; besti = p; }
  }
  float fr = 0.f;
  for (int p = tid; p < 4095; p += 1024) fr += (sel[p + 1] > sel[p]) ? 1.f : 0.f;

  sxx = wave_sum(sxx);
  syy = wave_sum(syy);
  sxy = wave_sum(sxy);
  mx = wave_max(mx);
  fr = wave_sum(fr);
#pragma unroll
  for (int off = 32; off >= 1; off >>= 1) {
    float ov = __shfl_xor(bestv, off, 64);
    int oi = __shfl_xor(besti, off, 64);
    if (ov < bestv || (ov == bestv && oi < besti)) { bestv = ov; besti = oi; }
  }
  if (ln == 0) {
    rA[wid] = sxx; rB[wid] = syy; rC[wid] = sxy;
    rD[wid] = mx;  rE[wid] = fr;  rV[wid] = bestv; rI[wid] = besti;
  }
  __syncthreads();
  if (tid == 0) {
    float tsxx = 0.f, tsyy = 0.f, tsxy = 0.f, tmx = -FLT_MAX, tfr = 0.f;
    float bv = FLT_MAX;
    int bi = 0x7fffffff;
    for (int i = 0; i < 16; ++i) {
      tsxx += rA[i]; tsyy += rB[i]; tsxy += rC[i];
      tmx = fmaxf(tmx, rD[i]); tfr += rE[i];
      if (rV[i] < bv || (rV[i] == bv && rI[i] < bi)) { bv = rV[i]; bi = rI[i]; }
    }
    float ne = el[bi];
    metrics_out[b * 5 + 0] = tmx - ne;
    metrics_out[b * 5 + 1] = sqrtf(tsyy / 4095.f);
    metrics_out[b * 5 + 2] = tsxy / sqrtf(tsxx * tsyy);
    metrics_out[b * 5 + 3] = tfr / 4095.f;
    metrics_out[b * 5 + 4] = ne;
  }
}

// ---------------------------------------------------------------------------
extern "C" void kernel_launch(void* const* d_in, const int* in_sizes, int n_in,
                              void* d_out, int out_size, void* d_ws, size_t ws_size,
                              hipStream_t stream) {
  const float* conf = (const float*)d_in[0];
  const float* native = (const float*)d_in[1];
  const float* We1 = (const float*)d_in[2];
  const float* be1 = (const float*)d_in[3];
  const float* We2 = (const float*)d_in[4];
  const float* be2 = (const float*)d_in[5];
  const float* We3 = (const float*)d_in[6];
  const float* be3 = (const float*)d_in[7];
  const float* Ws1 = (const float*)d_in[8];
  const float* bs1 = (const float*)d_in[9];
  const float* Ws2 = (const float*)d_in[10];
  const float* bs2 = (const float*)d_in[11];

  float* out = (float*)d_out;
  float* e_out = out;                 // [0, 16384)
  float* basin_out = out + BN;        // [16384, 32768)
  float* depth_out = out + 2 * BN;    // [32768, 49152)
  float* width_out = out + 3 * BN;    // [49152, 65536)
  float* logits_out = out + 4 * BN;   // [65536, 163840)
  float* metrics_out = out + 10 * BN; // [163840, 163860)

  float* wsf = (float*)d_ws;
  float* sq_ws = wsf;
  float* nd_ws = wsf + BN;
  float* se_ws = wsf + 2 * (size_t)BN;
  float* topd = wsf + 3 * (size_t)BN;

  // JS=8 needs: 3 + 80 (topd) + 40 (topi) + 102 (cbf) = 225 BN floats.
  const bool big = ws_size >= (size_t)225 * BN * 4;

  if (big) {
    unsigned short* topi = (unsigned short*)(wsf + 83 * (size_t)BN);   // 80BN topd
    unsigned short* cbf = (unsigned short*)(wsf + 123 * (size_t)BN);   // 40BN topi
    mlp_kernel<<<dim3(512), dim3(256), 0, stream>>>(
        conf, native, We1, be1, We2, be2, We3, be3, Ws1, bs1, Ws2, bs2,
        e_out, logits_out, sq_ws, nd_ws, cbf);
    topk_part_kernel<8><<<dim3(64, 8, NBATCH), dim3(256), 0, stream>>>(
        cbf, sq_ws, topd, topi);
    merge_rank_kernel<8><<<dim3(320), dim3(256), 0, stream>>>(
        topd, topi, e_out, nd_ws, basin_out, depth_out, width_out, se_ws);
  } else {
    unsigned short* topi = (unsigned short*)(wsf + 43 * (size_t)BN);   // 40BN topd
    unsigned short* cbf = (unsigned short*)(wsf + 63 * (size_t)BN);    // 20BN topi
    mlp_kernel<<<dim3(512), dim3(256), 0, stream>>>(
        conf, native, We1, be1, We2, be2, We3, be3, Ws1, bs1, Ws2, bs2,
        e_out, logits_out, sq_ws, nd_ws, cbf);
    topk_part_kernel<4><<<dim3(64, 4, NBATCH), dim3(256), 0, stream>>>(
        cbf, sq_ws, topd, topi);
    merge_rank_kernel<4><<<dim3(320), dim3(256), 0, stream>>>(
        topd, topi, e_out, nd_ws, basin_out, depth_out, width_out, se_ws);
  }
  metrics_kernel<<<dim3(NBATCH), dim3(1024), 0, stream>>>(e_out, nd_ws, se_ws, metrics_out);
}

// Round 16
// 196.870 us; speedup vs baseline: 1.1497x; 1.1497x over previous
//
#include <hip/hip_runtime.h>
#include <float.h>
#include <math.h>

#define NPTS 4096
#define NBATCH 4
#define BN (NBATCH * NPTS)   // 16384
#define EPSC 1e-12f
#define JS 4                 // j-dimension splits for the topk kernel
#define CSTRIDE 204          // ushort row stride of the bf16x3 image
#define NT (NPTS / JS / 64)  // 16 j-tiles per block

typedef __attribute__((ext_vector_type(8))) short bfrag;   // 8 bf16 (4 VGPR) MFMA operand
typedef __attribute__((ext_vector_type(4))) short bhalf;   // 8B half-fragment
typedef __attribute__((ext_vector_type(4))) float f32x4;   // MFMA accumulator

#define MFMA(A, B, C) __builtin_amdgcn_mfma_f32_16x16x32_bf16((A), (B), (C), 0, 0, 0)

__device__ __forceinline__ bool dless(float d1, int i1, float d2, int i2) {
  return (d1 < d2) || ((d1 == d2) && (i1 < i2));
}

// RN-even fp32->bf16 (branch-free), and back
__device__ __forceinline__ unsigned short f2bf(float x) {
  unsigned b = __float_as_uint(x);
  return (unsigned short)((b + 0x7FFFu + ((b >> 16) & 1u)) >> 16);
}
__device__ __forceinline__ float bf2f(unsigned short u) {
  return __uint_as_float(((unsigned)u) << 16);
}
// exact-ish 3-way split: x ~= bf(x0)+bf(x1)+bf(x2), residual ~2^-25|x|
__device__ __forceinline__ void bf3(float x, unsigned short& u0, unsigned short& u1,
                                    unsigned short& u2) {
  u0 = f2bf(x);
  float r = x - bf2f(u0);
  u1 = f2bf(r);
  r = r - bf2f(u1);
  u2 = f2bf(r);
}

// async global->LDS copies (no VGPR round-trip; wave-uniform base + lane*size)
__device__ __forceinline__ void cp16(const void* g, void* l) {
  __builtin_amdgcn_global_load_lds(
      (const __attribute__((address_space(1))) unsigned int*)g,
      (__attribute__((address_space(3))) unsigned int*)l, 16, 0, 0);
}
__device__ __forceinline__ void cp4(const void* g, void* l) {
  __builtin_amdgcn_global_load_lds(
      (const __attribute__((address_space(1))) unsigned int*)g,
      (__attribute__((address_space(3))) unsigned int*)l, 4, 0, 0);
}

// ---------------------------------------------------------------------------
// Kernel 1: fused MLP + bf16x3 image — e, logits, sq, nd, cbf.
// ---------------------------------------------------------------------------
__device__ __forceinline__ void gemm32x128(const float (*A)[64], const float* W,
                                           const float* bias, float (*O)[128], int tid) {
  const int pi = (tid >> 5) << 2;   // point quad
  const int ci = (tid & 31) << 2;   // col quad
  float acc[4][4] = {};
  for (int k0 = 0; k0 < 64; k0 += 4) {
    alignas(16) float av[4][4], wv[4][4];
#pragma unroll
    for (int r = 0; r < 4; ++r) *(float4*)av[r] = *(const float4*)&A[pi + r][k0];
#pragma unroll
    for (int kk = 0; kk < 4; ++kk) *(float4*)wv[kk] = *(const float4*)&W[(k0 + kk) * 128 + ci];
#pragma unroll
    for (int kk = 0; kk < 4; ++kk)
#pragma unroll
      for (int r = 0; r < 4; ++r)
#pragma unroll
        for (int c = 0; c < 4; ++c)
          acc[r][c] = fmaf(av[r][kk], wv[kk][c], acc[r][c]);
  }
#pragma unroll
  for (int r = 0; r < 4; ++r)
#pragma unroll
    for (int c = 0; c < 4; ++c)
      O[pi + r][ci + c] = fmaxf(acc[r][c] + bias[ci + c], 0.f);
}

__global__ __launch_bounds__(256) void mlp_kernel(
    const float* __restrict__ conf, const float* __restrict__ native,
    const float* __restrict__ We1, const float* __restrict__ be1,
    const float* __restrict__ We2, const float* __restrict__ be2,
    const float* __restrict__ We3, const float* __restrict__ be3,
    const float* __restrict__ Ws1, const float* __restrict__ bs1,
    const float* __restrict__ Ws2, const float* __restrict__ bs2,
    float* __restrict__ e_out, float* __restrict__ logits_out,
    float* __restrict__ sq_ws, float* __restrict__ nd_ws,
    unsigned short* __restrict__ cbf) {
  __shared__ __align__(16) float Wbuf[8192];       // 32 KB (We1 / We2 / Ws1)
  __shared__ __align__(16) float confs[32][64];    // 8 KB (later reused for h2)
  __shared__ __align__(16) float hbuf[32][128];    // 16 KB (g then h1)
  __shared__ float nat[64];
  __shared__ float b1s[128], b2s[64], w3s[64], bs1s[128], ws2s[768], bs2s[6];
  __shared__ float be3s;

  const int tid = threadIdx.x;
  const int blk = blockIdx.x;       // 0..511
  const int b = blk >> 7;           // 128 blocks per batch
  const int pbase = (blk & 127) * 32;
  const float* confb = conf + ((size_t)b * NPTS + pbase) * 64;

  for (int q = tid; q < 512; q += 256) {
    float4 v = *(const float4*)(confb + q * 4);
    *(float4*)&confs[q >> 4][(q & 15) << 2] = v;
  }
  if (tid < 64) nat[tid] = native[b * 64 + tid];
  if (tid < 128) b1s[tid] = be1[tid];
  if (tid < 64) b2s[tid] = be2[tid];
  if (tid < 64) w3s[tid] = We3[tid];
  if (tid < 128) bs1s[tid] = bs1[tid];
  for (int q = tid; q < 768; q += 256) ws2s[q] = Ws2[q];
  if (tid < 6) bs2s[tid] = bs2[tid];
  if (tid == 0) be3s = be3[0];
  for (int q = tid; q < 2048; q += 256)
    *(float4*)&Wbuf[q * 4] = *(const float4*)(Ws1 + q * 4);
  __syncthreads();

  // bf16x3 image of this 32-point tile
  for (int q = tid; q < 512; q += 256) {
    const int pl = q >> 4, k4 = (q & 15) << 2;
    float4 v = *(const float4*)&confs[pl][k4];
    unsigned short x0, x1, x2, y0, y1, y2, z0, z1, z2, w0, w1, w2;
    bf3(v.x, x0, x1, x2);
    bf3(v.y, y0, y1, y2);
    bf3(v.z, z0, z1, z2);
    bf3(v.w, w0, w1, w2);
    unsigned short* dst = cbf + (size_t)(b * NPTS + pbase + pl) * CSTRIDE + k4;
    *(bhalf*)&dst[0] = (bhalf){(short)x0, (short)y0, (short)z0, (short)w0};
    *(bhalf*)&dst[64] = (bhalf){(short)x1, (short)y1, (short)z1, (short)w1};
    *(bhalf*)&dst[128] = (bhalf){(short)x2, (short)y2, (short)z2, (short)w2};
  }

  // sq & nd — numpy-pairwise style: rounded products, 8 accumulators
  if (tid < 32) {
    float rs_[8], rn_[8];
#pragma unroll
    for (int u = 0; u < 8; ++u) {
      float c = confs[tid][u];
      rs_[u] = c * c;
      float d = c - nat[u];
      rn_[u] = d * d;
    }
    for (int d0 = 8; d0 < 64; d0 += 8) {
#pragma unroll
      for (int u = 0; u < 8; ++u) {
        float c = confs[tid][d0 + u];
        rs_[u] += c * c;
        float d = c - nat[d0 + u];
        rn_[u] += d * d;
      }
    }
    float s = ((rs_[0] + rs_[1]) + (rs_[2] + rs_[3])) + ((rs_[4] + rs_[5]) + (rs_[6] + rs_[7]));
    float n = ((rn_[0] + rn_[1]) + (rn_[2] + rn_[3])) + ((rn_[4] + rn_[5]) + (rn_[6] + rn_[7]));
    sq_ws[(size_t)b * NPTS + pbase + tid] = s;
    nd_ws[(size_t)b * NPTS + pbase + tid] = sqrtf(n);
  }

  gemm32x128(confs, Wbuf, bs1s, hbuf, tid);     // g = relu(conf @ Ws1 + bs1)
  __syncthreads();

  for (int q = tid; q < 2048; q += 256)         // reload Wbuf <- We1
    *(float4*)&Wbuf[q * 4] = *(const float4*)(We1 + q * 4);
  if (tid < 192) {
    int p = tid / 6, s = tid % 6;
    float acc = 0.f;
#pragma unroll 8
    for (int h = 0; h < 128; ++h)
      acc = fmaf(hbuf[p][h], ws2s[h * 6 + s], acc);
    logits_out[((size_t)b * NPTS + pbase + p) * 6 + s] = acc + bs2s[s];
  }
  __syncthreads();

  gemm32x128(confs, Wbuf, b1s, hbuf, tid);      // h1 = relu(conf @ We1 + be1)
  __syncthreads();

  for (int q = tid; q < 2048; q += 256)
    *(float4*)&Wbuf[q * 4] = *(const float4*)(We2 + q * 4);
  __syncthreads();

  // h2 = relu(h1 @ We2 + be2) -> confs
  if (tid < 128) {
    const int pi = (tid >> 4) << 2;
    const int ci = (tid & 15) << 2;
    float acc[4][4] = {};
    for (int k0 = 0; k0 < 128; k0 += 4) {
      alignas(16) float av[4][4], wv[4][4];
#pragma unroll
      for (int r = 0; r < 4; ++r) *(float4*)av[r] = *(const float4*)&hbuf[pi + r][k0];
#pragma unroll
      for (int kk = 0; kk < 4; ++kk) *(float4*)wv[kk] = *(const float4*)&Wbuf[(k0 + kk) * 64 + ci];
#pragma unroll
      for (int kk = 0; kk < 4; ++kk)
#pragma unroll
        for (int r = 0; r < 4; ++r)
#pragma unroll
          for (int c = 0; c < 4; ++c)
            acc[r][c] = fmaf(av[r][kk], wv[kk][c], acc[r][c]);
    }
#pragma unroll
    for (int r = 0; r < 4; ++r)
#pragma unroll
      for (int c = 0; c < 4; ++c)
        confs[pi + r][ci + c] = fmaxf(acc[r][c] + b2s[ci + c], 0.f);
  }
  __syncthreads();

  if (tid < 32) {                               // e = h2 @ We3 + be3
    float acc = 0.f;
#pragma unroll
    for (int k = 0; k < 64; ++k)
      acc = fmaf(confs[tid][k], w3s[k], acc);
    e_out[(size_t)b * NPTS + pbase + tid] = acc + be3s;
  }
}

// ---------------------------------------------------------------------------
// Distance pass (split-j), bf16x3 MFMA, d2-keyed, mask-queued top-10.
// Staging via global_load_lds (async DMA, zero VGPR). Drain is software-
// pipelined: pop k+1's LDS read is issued before pop k's bubble, hiding
// ds_read latency under the insert VALU.
// ---------------------------------------------------------------------------
__device__ __forceinline__ bfrag ldfrag(const unsigned short* p) {
  bhalf lo = *(const bhalf*)p;        // 8B aligned
  bhalf hi = *(const bhalf*)(p + 4);  // +8B
  return __builtin_shufflevector(lo, hi, 0, 1, 2, 3, 4, 5, 6, 7);
}

// stage one 64-row bf16x3 tile (1632 x 16B) + 64 sq floats, async
__device__ __forceinline__ void stage_async(const unsigned short* src,
                                            unsigned short* BU,
                                            const float* sqsrc, float* sqjs,
                                            int tid) {
  const char* s = (const char*)src;
  char* d = (char*)BU;
#pragma unroll
  for (int it = 0; it < 6; ++it) {
    const int q = it * 256 + tid;
    cp16(s + (size_t)q * 16, d + (size_t)q * 16);
  }
  if (tid < 96) {
    const int q = 1536 + tid;
    cp16(s + (size_t)q * 16, d + (size_t)q * 16);
  }
  if (tid < 64) cp4(sqsrc + tid, sqjs + tid);
}

__global__ __launch_bounds__(256, 1) void topk_part_kernel(
    const unsigned short* __restrict__ cbf, const float* __restrict__ sq_ws,
    float* __restrict__ topd, unsigned short* __restrict__ topi) {
  __shared__ __align__(16) unsigned short BU[64 * CSTRIDE];  // 26112 B (B tile; reused as mrgI)
  __shared__ __align__(16) float Dsf[64 * 68];               // 17408 B (cd2 tile; reused as mrgD)
  __shared__ float sqjs[64];

  const int tid = threadIdx.x;
  const int b = blockIdx.z;
  const int i0 = blockIdx.x * 64;
  const int jbase = blockIdx.y * (NPTS / JS);
  const unsigned short* cbfb = cbf + (size_t)b * NPTS * CSTRIDE;
  const float* sqb = sq_ws + (size_t)b * NPTS;

  const int l = tid & 63, w = tid >> 6;   // lane, wave (wave w owns rows 16w..16w+15)
  const int cl = l & 15, g = l >> 4;

  // A-fragments straight from global (one-time; 6 x 2 x 8B loads per lane)
  const unsigned short* arow = cbfb + (size_t)(i0 + 16 * w + cl) * CSTRIDE + g * 8;
  const bfrag a00 = ldfrag(arow + 0);
  const bfrag a01 = ldfrag(arow + 32);
  const bfrag a10 = ldfrag(arow + 64);
  const bfrag a11 = ldfrag(arow + 96);
  const bfrag a20 = ldfrag(arow + 128);
  const bfrag a21 = ldfrag(arow + 160);
  float sqar[4];
#pragma unroll
  for (int e = 0; e < 4; ++e) sqar[e] = sqb[i0 + 16 * w + 4 * g + e];

  const int irow = tid >> 2, q4 = tid & 3;   // queue-phase mapping (4 thr/row)

  unsigned long long lk[10];
#pragma unroll
  for (int k = 0; k < 10; ++k) lk[k] = 0x7F7FFFFF7FFFFFFFULL;  // (FLT_MAX, INT_MAX)
  float thrf = FLT_MAX;

  // prologue: async stage tile 0
  stage_async(cbfb + (size_t)jbase * CSTRIDE, BU, sqb + jbase, sqjs, tid);
  __syncthreads();   // drains vmcnt -> BU/sqjs ready

  for (int jt = 0; jt < NT; ++jt) {
    const int j0 = jbase + jt * 64;

    // ---- MFMA: 4 col-subtiles of 16, 12 k-steps each (6 B-frags, 2x reuse)
#pragma unroll
    for (int c = 0; c < 4; ++c) {
      const unsigned short* bp = &BU[(16 * c + cl) * CSTRIDE + g * 8];
      const bfrag b00 = ldfrag(bp + 0);
      const bfrag b01 = ldfrag(bp + 32);
      const bfrag b10 = ldfrag(bp + 64);
      const bfrag b11 = ldfrag(bp + 96);
      const bfrag b20 = ldfrag(bp + 128);
      const bfrag b21 = ldfrag(bp + 160);
      f32x4 acc = {0.f, 0.f, 0.f, 0.f};
      acc = MFMA(a00, b00, acc); acc = MFMA(a01, b01, acc);   // A0*B0
      acc = MFMA(a00, b10, acc); acc = MFMA(a01, b11, acc);   // A0*B1
      acc = MFMA(a10, b00, acc); acc = MFMA(a11, b01, acc);   // A1*B0
      acc = MFMA(a00, b20, acc); acc = MFMA(a01, b21, acc);   // A0*B2
      acc = MFMA(a10, b10, acc); acc = MFMA(a11, b11, acc);   // A1*B1
      acc = MFMA(a20, b00, acc); acc = MFMA(a21, b01, acc);   // A2*B0
      const int col = 16 * c + cl;
      const float sj = sqjs[col];
#pragma unroll
      for (int e = 0; e < 4; ++e) {
        const int rw = 16 * w + 4 * g + e;
        float d2 = fmaf(-2.f, acc[e], sqar[e] + sj);
        Dsf[rw * 68 + col] = fmaxf(d2, EPSC);   // cd2 (sqrt deferred)
      }
    }
    __syncthreads();   // Ds ready; BU/sqjs consumed by MFMA

    // ---- async-stage next tile (flies across the queue/drain below)
    if (jt + 1 < NT)
      stage_async(cbfb + (size_t)(j0 + 64) * CSTRIDE, BU, sqb + j0 + 64, sqjs, tid);

    // ---- queue phase: 16-bit pass mask (ascending bit = ascending j)
    const float* drow = &Dsf[irow * 68 + q4 * 16];
    unsigned mask = 0;
#pragma unroll
    for (int cc = 0; cc < 4; ++cc) {
      float4 v = *(const float4*)&drow[cc * 4];
      mask |= (v.x <= thrf) ? (1u << (cc * 4 + 0)) : 0u;
      mask |= (v.y <= thrf) ? (1u << (cc * 4 + 1)) : 0u;
      mask |= (v.z <= thrf) ? (1u << (cc * 4 + 2)) : 0u;
      mask |= (v.w <= thrf) ? (1u << (cc * 4 + 3)) : 0u;
    }
    const int cnt = __popc(mask);
    int K = cnt;
#pragma unroll
    for (int off = 32; off >= 1; off >>= 1) K = max(K, __shfl_xor(K, off, 64));

    // ---- pipelined drain: prefetch pop k+1's read before pop k's bubble
    int id = (__ffs(mask) - 1) & 15;   // mask==0 -> 15 (valid dummy read)
    mask &= mask - 1;
    float dcur = drow[id];
    int jcur = j0 + q4 * 16 + id;
    for (int k = 0; k < K; ++k) {
      const int idn = (__ffs(mask) - 1) & 15;
      mask &= mask - 1;
      const float dnx = drow[idn];             // issued before the bubble
      const int jnx = j0 + q4 * 16 + idn;
      if (k < cnt) {
        unsigned long long cur =
            (((unsigned long long)__float_as_uint(dcur)) << 32) |
            (unsigned long long)(unsigned)jcur;
        if (cur < lk[9]) {
#pragma unroll
          for (int kk = 0; kk < 10; ++kk) {
            bool lt = cur < lk[kk];
            unsigned long long mn = lt ? cur : lk[kk];
            cur = lt ? lk[kk] : cur;
            lk[kk] = mn;
          }
        }
      }
      dcur = dnx;
      jcur = jnx;
    }

    // refresh row-wide filter bound: min of the 4 siblings' 10th cd2
    float t = __uint_as_float((unsigned)(lk[9] >> 32));
    t = fminf(t, __shfl_xor(t, 1, 4));
    t = fminf(t, __shfl_xor(t, 2, 4));
    thrf = t;
    __syncthreads();   // drains vmcnt -> BU(t+1)/sqjs ready; Ds consumed
  }

  // merge 4 per-thread sorted lists per row -> chunk top-10 (cd2), write to ws
  float* mrgD = Dsf;          // 2560 floats
  int* mrgI = (int*)BU;       // 2560 ints
  {
#pragma unroll
    for (int k = 0; k < 10; ++k) {
      mrgD[irow * 40 + q4 * 10 + k] = __uint_as_float((unsigned)(lk[k] >> 32));
      mrgI[irow * 40 + q4 * 10 + k] = (int)(unsigned)(lk[k] & 0xFFFFFFFFu);
    }
  }
  __syncthreads();
  if (tid < 64) {
    const int base = tid * 40;
    int h0 = 0, h1 = 0, h2 = 0, h3 = 0;
    const size_t obase = (((size_t)b * NPTS + i0 + tid) * JS + blockIdx.y) * 10;
    for (int k = 0; k < 10; ++k) {
      float bd = FLT_MAX; int bi = 0x7fffffff; int bl = -1;
      { float d = mrgD[base + h0];      int ii = mrgI[base + h0];      if (dless(d, ii, bd, bi)) { bd = d; bi = ii; bl = 0; } }
      { float d = mrgD[base + 10 + h1]; int ii = mrgI[base + 10 + h1]; if (dless(d, ii, bd, bi)) { bd = d; bi = ii; bl = 1; } }
      { float d = mrgD[base + 20 + h2]; int ii = mrgI[base + 20 + h2]; if (dless(d, ii, bd, bi)) { bd = d; bi = ii; bl = 2; } }
      { float d = mrgD[base + 30 + h3]; int ii = mrgI[base + 30 + h3]; if (dless(d, ii, bd, bi)) { bd = d; bi = ii; bl = 3; } }
      h0 += (bl == 0); h1 += (bl == 1); h2 += (bl == 2); h3 += (bl == 3);
      topd[obase + k] = bd;                    // cd2
      topi[obase + k] = (unsigned short)bi;
    }
  }
}

// ---------------------------------------------------------------------------
// Fused merge (blocks 0..63) + rank (blocks 64..319).
// ---------------------------------------------------------------------------
__global__ __launch_bounds__(256) void merge_rank_kernel(
    const float* __restrict__ topd, const unsigned short* __restrict__ topi,
    const float* __restrict__ e_in, const float* __restrict__ nd_ws,
    float* __restrict__ basin_out, float* __restrict__ depth_out,
    float* __restrict__ width_out, float* __restrict__ se_ws) {
  __shared__ __align__(16) float ndl[4096];
  const int tid = threadIdx.x;
  if (blockIdx.x < 64) {
    // ---- merge role
    const int g = blockIdx.x * 256 + tid;   // 0..16383
    const int b = g >> 12;
    const float* eb = e_in + (size_t)b * NPTS;
    const float* td = topd + (size_t)g * (JS * 10);
    const unsigned short* ti = topi + (size_t)g * (JS * 10);
    const float e_i = eb[g & (NPTS - 1)];
    int h0 = 0, h1 = 0, h2 = 0, h3 = 0;
    float dk[10];
    int ik[10];
#pragma unroll
    for (int k = 0; k < 10; ++k) {
      float bd = FLT_MAX; int bi = 0x7fffffff; int bl = -1;
      { float d = td[h0];      int ii = ti[h0];      if (dless(d, ii, bd, bi)) { bd = d; bi = ii; bl = 0; } }
      { float d = td[10 + h1]; int ii = ti[10 + h1]; if (dless(d, ii, bd, bi)) { bd = d; bi = ii; bl = 1; } }
      { float d = td[20 + h2]; int ii = ti[20 + h2]; if (dless(d, ii, bd, bi)) { bd = d; bi = ii; bl = 2; } }
      { float d = td[30 + h3]; int ii = ti[30 + h3]; if (dless(d, ii, bd, bi)) { bd = d; bi = ii; bl = 3; } }
      h0 += (bl == 0); h1 += (bl == 1); h2 += (bl == 2); h3 += (bl == 3);
      dk[k] = bd;
      ik[k] = bi;
    }
    const float r2 = dk[9];
    bool basin = true;
    float mx = -FLT_MAX, sum = 0.f, cnt = 0.f;
#pragma unroll
    for (int k = 0; k < 10; ++k) {
      float ev = eb[ik[k]];
      if (dk[k] < r2) { mx = fmaxf(mx, ev); sum += sqrtf(dk[k]); cnt += 1.f; }
      if (k >= 1) basin = basin && (e_i <= ev);
    }
    basin_out[g] = basin ? 1.f : 0.f;
    depth_out[g] = mx - e_i;
    width_out[g] = sum / cnt;
  } else {
    // ---- rank role
    const int rb = blockIdx.x - 64;   // 0..255
    const int b = rb >> 6;
    const int i0 = (rb & 63) * 64;
    const float* ndb = nd_ws + (size_t)b * NPTS;
    for (int q = tid; q < 1024; q += 256)
      *(float4*)&ndl[q * 4] = *(const float4*)(ndb + q * 4);
    __syncthreads();
    const int i = i0 + (tid >> 2);
    const int qp = tid & 3;
    const float ndi = ndl[i];
    int rank = 0;
    for (int j = qp * 1024; j < qp * 1024 + 1024; j += 4) {
      float4 v = *(const float4*)&ndl[j];
      rank += (v.x < ndi) || (v.x == ndi && (j + 0) < i);
      rank += (v.y < ndi) || (v.y == ndi && (j + 1) < i);
      rank += (v.z < ndi) || (v.z == ndi && (j + 2) < i);
      rank += (v.w < ndi) || (v.w == ndi && (j + 3) < i);
    }
    rank += __shfl_xor(rank, 1, 4);
    rank += __shfl_xor(rank, 2, 4);
    if (qp == 0) se_ws[(size_t)b * NPTS + rank] = e_in[(size_t)b * NPTS + i];
  }
}

// ---------------------------------------------------------------------------
// Kernel 4: per-batch scalar metrics — wave-level reductions
// ---------------------------------------------------------------------------
__device__ __forceinline__ float wave_sum(float v) {
#pragma unroll
  for (int off = 32; off >= 1; off >>= 1) v += __shfl_xor(v, off, 64);
  return v;
}
__device__ __forceinline__ float wave_max(float v) {
#pragma unroll
  for (int off = 32; off >= 1; off >>= 1) v = fmaxf(v, __shfl_xor(v, off, 64));
  return v;
}

__global__ __launch_bounds__(1024) void metrics_kernel(
    const float* __restrict__ e_in, const float* __restrict__ nd_ws,
    const float* __restrict__ se_ws, float* __restrict__ metrics_out) {
  __shared__ __align__(16) float el[4096], ndl[4096], sel[4096];
  __shared__ float rA[16], rB[16], rC[16], rD[16], rE[16], rV[16];
  __shared__ int rI[16];
  const int tid = threadIdx.x;
  const int b = blockIdx.x;
  const int wid = tid >> 6, ln = tid & 63;
  const float* eb = e_in + (size_t)b * NPTS;
  const float* ndb = nd_ws + (size_t)b * NPTS;
  const float* seb = se_ws + (size_t)b * NPTS;
  *(float4*)&el[tid * 4] = *(const float4*)(eb + tid * 4);
  *(float4*)&ndl[tid * 4] = *(const float4*)(ndb + tid * 4);
  *(float4*)&sel[tid * 4] = *(const float4*)(seb + tid * 4);
  __syncthreads();

  float pe = 0.f, pnd = 0.f;
  for (int p = tid; p < 4096; p += 1024) { pe += el[p]; pnd += ndl[p]; }
  pe = wave_sum(pe);
  pnd = wave_sum(pnd);
  if (ln == 0) { rA[wid] = pe; rB[wid] = pnd; }
  __syncthreads();
  float me = 0.f, mnd = 0.f;
  for (int i = 0; i < 16; ++i) { me += rA[i]; mnd += rB[i]; }
  me /= 4096.f;
  mnd /= 4096.f;
  __syncthreads();

  float sxx = 0.f, syy = 0.f, sxy = 0.f, mx = -FLT_MAX;
  float bestv = FLT_MAX;
  int besti = 0x7fffffff;
  for (int p = tid; p < 4096; p += 1024) {
    float de = el[p] - me, dn = ndl[p] - mnd;
    syy += de * de;
    sxx += dn * dn;
    sxy += de * dn;
    mx = fmaxf(mx, el[p]);
    if (ndl[p] < bestv || (ndl[p] == bestv && p < besti)) { bestv = ndl[p]; besti = p; }
  }
  float fr = 0.f;
  for (int p = tid; p < 4095; p += 1024) fr += (sel[p + 1] > sel[p]) ? 1.f : 0.f;

  sxx = wave_sum(sxx);
  syy = wave_sum(syy);
  sxy = wave_sum(sxy);
  mx = wave_max(mx);
  fr = wave_sum(fr);
#pragma unroll
  for (int off = 32; off >= 1; off >>= 1) {
    float ov = __shfl_xor(bestv, off, 64);
    int oi = __shfl_xor(besti, off, 64);
    if (ov < bestv || (ov == bestv && oi < besti)) { bestv = ov; besti = oi; }
  }
  if (ln == 0) {
    rA[wid] = sxx; rB[wid] = syy; rC[wid] = sxy;
    rD[wid] = mx;  rE[wid] = fr;  rV[wid] = bestv; rI[wid] = besti;
  }
  __syncthreads();
  if (tid == 0) {
    float tsxx = 0.f, tsyy = 0.f, tsxy = 0.f, tmx = -FLT_MAX, tfr = 0.f;
    float bv = FLT_MAX;
    int bi = 0x7fffffff;
    for (int i = 0; i < 16; ++i) {
      tsxx += rA[i]; tsyy += rB[i]; tsxy += rC[i];
      tmx = fmaxf(tmx, rD[i]); tfr += rE[i];
      if (rV[i] < bv || (rV[i] == bv && rI[i] < bi)) { bv = rV[i]; bi = rI[i]; }
    }
    float ne = el[bi];
    metrics_out[b * 5 + 0] = tmx - ne;
    metrics_out[b * 5 + 1] = sqrtf(tsyy / 4095.f);
    metrics_out[b * 5 + 2] = tsxy / sqrtf(tsxx * tsyy);
    metrics_out[b * 5 + 3] = tfr / 4095.f;
    metrics_out[b * 5 + 4] = ne;
  }
}

// ---------------------------------------------------------------------------
extern "C" void kernel_launch(void* const* d_in, const int* in_sizes, int n_in,
                              void* d_out, int out_size, void* d_ws, size_t ws_size,
                              hipStream_t stream) {
  const float* conf = (const float*)d_in[0];
  const float* native = (const float*)d_in[1];
  const float* We1 = (const float*)d_in[2];
  const float* be1 = (const float*)d_in[3];
  const float* We2 = (const float*)d_in[4];
  const float* be2 = (const float*)d_in[5];
  const float* We3 = (const float*)d_in[6];
  const float* be3 = (const float*)d_in[7];
  const float* Ws1 = (const float*)d_in[8];
  const float* bs1 = (const float*)d_in[9];
  const float* Ws2 = (const float*)d_in[10];
  const float* bs2 = (const float*)d_in[11];

  float* out = (float*)d_out;
  float* e_out = out;                 // [0, 16384)
  float* basin_out = out + BN;        // [16384, 32768)
  float* depth_out = out + 2 * BN;    // [32768, 49152)
  float* width_out = out + 3 * BN;    // [49152, 65536)
  float* logits_out = out + 4 * BN;   // [65536, 163840)
  float* metrics_out = out + 10 * BN; // [163840, 163860)

  // ws layout (floats): sq | nd | se | topd(40BN) | topi(20BN) | cbf(102BN)
  float* wsf = (float*)d_ws;
  float* sq_ws = wsf;
  float* nd_ws = wsf + BN;
  float* se_ws = wsf + 2 * (size_t)BN;
  float* topd = wsf + 3 * (size_t)BN;
  unsigned short* topi = (unsigned short*)(wsf + 43 * (size_t)BN);
  unsigned short* cbf = (unsigned short*)(wsf + 63 * (size_t)BN);

  mlp_kernel<<<dim3(512), dim3(256), 0, stream>>>(
      conf, native, We1, be1, We2, be2, We3, be3, Ws1, bs1, Ws2, bs2,
      e_out, logits_out, sq_ws, nd_ws, cbf);
  topk_part_kernel<<<dim3(64, JS, NBATCH), dim3(256), 0, stream>>>(
      cbf, sq_ws, topd, topi);
  merge_rank_kernel<<<dim3(320), dim3(256), 0, stream>>>(
      topd, topi, e_out, nd_ws, basin_out, depth_out, width_out, se_ws);
  metrics_kernel<<<dim3(NBATCH), dim3(1024), 0, stream>>>(e_out, nd_ws, se_ws, metrics_out);
}